// Round 8
// baseline (291.435 us; speedup 1.0000x reference)
//
#include <hip/hip_runtime.h>
#include <stdint.h>

// Bahdanau additive attention, MI355X / gfx950.
// Inputs fp32, outputs fp32 (ctx[32*512] ++ aw[32*2048]).
// B=32, T=2048, D=512, U=512.  M = B*T = 65536.
//
// R16: phase-split k-loop (T3/T5 port) on R2's verified geometry.
//      R15 falsified the drain theory (counted vmcnt = null); R2's real limit
//      is lockstep burst serialization + tiny per-barrier MFMA work (16/wave).
//      Now: BK=64 (8 steps, 32 MFMA/wave/step), 4 phases/step each
//      {a_next/ds_read x6 / stage x2 -> s_barrier -> setprio(1) 8 MFMA},
//      one __syncthreads per step. LDS = 160KB exactly:
//      Bs[2][512x64] + As[2][128x64], 128B rows XOR-swizzled chunk^=(row&7)
//      (B: pre-swizzled GLOBAL source, gload_lds dest linear [R8 pattern];
//       A: reg-staged ds_write, dest swizzle legal). uh/Vk -> epilogue regs;
//      lpart overlays As. Fragment semantics/bit-layout identical to R2.
// R15: counted-vmcnt null. R13/R12/R11: rewrites regressed. R10: no atomics.

typedef unsigned short ushort_t;
typedef __attribute__((ext_vector_type(8))) short short8;
typedef __attribute__((ext_vector_type(4))) float f32x4;
typedef __attribute__((ext_vector_type(4))) uint32_t u32x4;
typedef __attribute__((ext_vector_type(2))) float float2v;
typedef __attribute__((ext_vector_type(2))) __bf16 bf162v;

#define GLOBAL_AS __attribute__((address_space(1)))
#define LDS_AS    __attribute__((address_space(3)))

__device__ __forceinline__ ushort_t f2bf(float f) {
    uint32_t u = __builtin_bit_cast(uint32_t, f);
    u = (u + 0x7fffu + ((u >> 16) & 1u)) >> 16;   // RNE
    return (ushort_t)u;
}
__device__ __forceinline__ uint32_t pkbf(float a, float b) {
    bf162v r = __builtin_convertvector((float2v){a, b}, bf162v);
    return __builtin_bit_cast(uint32_t, r);
}

// --------------------------- fused prep: uh GEMV + WkT transpose (R2 verbatim)
// grid 512 = 256 uh | 256 WkT.  WkT[u][d] = bf16(Wk[d][u]).
__global__ __launch_bounds__(256) void prep_all(
    const float* __restrict__ hidden, const float* __restrict__ Uk,
    const float* __restrict__ Ub, const float* __restrict__ Wb,
    const float* __restrict__ Wk,
    float* __restrict__ uh, ushort_t* __restrict__ WkT)
{
    const int pb = blockIdx.x;
    if (pb < 256) {
        const int b  = pb >> 3;
        const int u  = (pb & 7) * 64 + (threadIdx.x & 63);
        const int k0 = (threadIdx.x >> 6) * 128;
        const float* hr = hidden + b * 512;
        float acc = 0.f;
        #pragma unroll 8
        for (int k = k0; k < k0 + 128; ++k)
            acc += hr[k] * Uk[k * 512 + u];
        __shared__ float red[256];
        red[threadIdx.x] = acc;
        __syncthreads();
        if (threadIdx.x < 64) {
            const int ul = threadIdx.x;
            uh[b * 512 + u] = red[ul] + red[ul + 64] + red[ul + 128] + red[ul + 192]
                            + Ub[u] + Wb[u];
        }
    } else {
        __shared__ float t[32][33];
        const int blk = pb - 256;
        const int ti = blk >> 4;
        const int tj = blk & 15;
        const int tx = threadIdx.x & 31;
        const int ty = threadIdx.x >> 5;
        #pragma unroll
        for (int q = 0; q < 4; ++q) {
            const int r = ty * 4 + q;
            t[r][tx] = Wk[(ti * 32 + r) * 512 + tj * 32 + tx];
        }
        __syncthreads();
        #pragma unroll
        for (int q = 0; q < 4; ++q) {
            const int r = ty * 4 + q;
            WkT[(tj * 32 + r) * 512 + ti * 32 + tx] = f2bf(t[tx][r]);
        }
    }
}

// ------------------------------------------------ fused GEMM+tanh+Vk-dot
// grid 512 M-tiles of 128 rows; 1024 threads = 16 waves (2M x 8N, 64x64).
// BK=64, 8 k-steps, 4 phases/step. LDS 160KB exactly (1 block/CU).
#define MFMA_B16(a, b, c) __builtin_amdgcn_mfma_f32_16x16x32_bf16(a, b, c, 0, 0, 0)
__global__ __launch_bounds__(1024, 4) void attn_gemm(
    const float* __restrict__ feats, const ushort_t* __restrict__ WkT,
    const float* __restrict__ uh, const float* __restrict__ Vk,
    float* __restrict__ lg)
{
    __shared__ __align__(16) short As[2][128 * 64];   // 2 x 16 KB
    __shared__ __align__(16) short Bs[2][512 * 64];   // 2 x 64 KB

    const int tid  = threadIdx.x;
    const int lane = tid & 63;
    const int quad = lane >> 4;
    const int lc   = lane & 15;
    const int wave = tid >> 6;       // 0..15
    const int wm   = wave >> 3;      // 0..1  (64-row strip)
    const int wn   = wave & 7;       // 0..7  (64-col strip)
    const int m0   = blockIdx.x * 128;
    const int bidx = m0 >> 11;       // batch index (uniform per block)

    // read offsets (bytes). row stride 128B; chunk c stored at c^(row&7).
    // reads want global chunk h*4+quad -> lds chunk (h*4+quad)^(row&7).
    int ofsA[4][2], ofsB[4][2];
    #pragma unroll
    for (int m = 0; m < 4; ++m) {
        const int r = wm * 64 + m * 16 + lc;
        #pragma unroll
        for (int h = 0; h < 2; ++h)
            ofsA[m][h] = r * 128 + (((h * 4 + quad) ^ (r & 7)) * 16);
    }
    #pragma unroll
    for (int n = 0; n < 4; ++n) {
        const int r = wn * 64 + n * 16 + lc;
        #pragma unroll
        for (int h = 0; h < 2; ++h)
            ofsB[n][h] = r * 128 + (((h * 4 + quad) ^ (r & 7)) * 16);
    }

    // A staging: thread t -> feats row rowA, global chunk cA (8 fp32 = 32B),
    // ds_write 16B bf16 at swizzled chunk cA^(rowA&7).
    const int rowA = tid >> 3;
    const int cA   = tid & 7;
    const int dstA = rowA * 128 + ((cA ^ (rowA & 7)) * 16);   // byte
    const float* apb = feats + (size_t)(m0 + rowA) * 512 + cA * 8;

    // B staging: 4 rounds x 16B/thread; dest lane-linear (HW requirement),
    // source chunk pre-swizzled: lds chunk sB of row rB holds global chunk
    // sB^(rB&7)  ->  src elem = rB*512 + (sB^(rB&7))*8 (+ k base).
    int srcB[4], dstB[4];
    #pragma unroll
    for (int rnd = 0; rnd < 4; ++rnd) {
        const int li = rnd * 1024 + tid;
        const int rB = li >> 3;
        const int sB = tid & 7;
        srcB[rnd] = rB * 512 + ((sB ^ (rB & 7)) * 8);
        dstB[rnd] = li * 16;                          // byte
    }

    f32x4 acc[4][4];
    #pragma unroll
    for (int tm = 0; tm < 4; ++tm)
        #pragma unroll
        for (int tn = 0; tn < 4; ++tn)
            acc[tm][tn] = (f32x4){0.f, 0.f, 0.f, 0.f};

    // ---- prologue: stage B(0) -> Bs[0], A(0) -> As[0]
    {
        #pragma unroll
        for (int rnd = 0; rnd < 4; ++rnd)
            __builtin_amdgcn_global_load_lds(
                (const GLOBAL_AS void*)(WkT + srcB[rnd]),
                (LDS_AS void*)((char*)Bs[0] + dstB[rnd]), 16, 0, 0);
        const f32x4 a0 = *(const f32x4*)(apb);
        const f32x4 a1 = *(const f32x4*)(apb + 4);
        u32x4 w = (u32x4){pkbf(a0.x, a0.y), pkbf(a0.z, a0.w),
                          pkbf(a1.x, a1.y), pkbf(a1.z, a1.w)};
        *(u32x4*)((char*)As[0] + dstA) = w;
    }

    int buf = 0;
    for (int ks = 0; ks < 8; ++ks) {    // K = 512, BK = 64
        __syncthreads();                // buf staged (stages are ~3 phases old)
        const short* Ab = As[buf];
        const short* Bb = Bs[buf];
        short* Bn = Bs[buf ^ 1];
        const bool have = (ks + 1) < 8;

        f32x4 an0, an1;
        if (have) {                     // oldest VMEM this step: its use-wait
            an0 = *(const f32x4*)(apb + (ks + 1) * 64);       // leaves stages
            an1 = *(const f32x4*)(apb + (ks + 1) * 64 + 4);   // in flight
        }

        // ---- Ph0: ds_read h0 {B n0..3, A m0,m1}; stage rnd0,1; MFMA h0 m01
        short8 bf0[4], af0, af1;
        #pragma unroll
        for (int n = 0; n < 4; ++n)
            bf0[n] = *(const short8*)((const char*)Bb + ofsB[n][0]);
        af0 = *(const short8*)((const char*)Ab + ofsA[0][0]);
        af1 = *(const short8*)((const char*)Ab + ofsA[1][0]);
        if (have) {
            const int kb = (ks + 1) * 64;
            __builtin_amdgcn_global_load_lds(
                (const GLOBAL_AS void*)(WkT + kb + srcB[0]),
                (LDS_AS void*)((char*)Bn + dstB[0]), 16, 0, 0);
            __builtin_amdgcn_global_load_lds(
                (const GLOBAL_AS void*)(WkT + kb + srcB[1]),
                (LDS_AS void*)((char*)Bn + dstB[1]), 16, 0, 0);
        }
        __builtin_amdgcn_sched_barrier(0);
        __builtin_amdgcn_s_barrier();
        __builtin_amdgcn_s_setprio(1);
        #pragma unroll
        for (int n = 0; n < 4; ++n) {
            acc[0][n] = MFMA_B16(af0, bf0[n], acc[0][n]);
            acc[1][n] = MFMA_B16(af1, bf0[n], acc[1][n]);
        }
        __builtin_amdgcn_s_setprio(0);
        __builtin_amdgcn_sched_barrier(0);

        // ---- Ph1: ds_read h0 {A m2,m3}; stage rnd2,3; MFMA h0 m23
        short8 af2 = *(const short8*)((const char*)Ab + ofsA[2][0]);
        short8 af3 = *(const short8*)((const char*)Ab + ofsA[3][0]);
        if (have) {
            const int kb = (ks + 1) * 64;
            __builtin_amdgcn_global_load_lds(
                (const GLOBAL_AS void*)(WkT + kb + srcB[2]),
                (LDS_AS void*)((char*)Bn + dstB[2]), 16, 0, 0);
            __builtin_amdgcn_global_load_lds(
                (const GLOBAL_AS void*)(WkT + kb + srcB[3]),
                (LDS_AS void*)((char*)Bn + dstB[3]), 16, 0, 0);
        }
        __builtin_amdgcn_sched_barrier(0);
        __builtin_amdgcn_s_barrier();
        __builtin_amdgcn_s_setprio(1);
        #pragma unroll
        for (int n = 0; n < 4; ++n) {
            acc[2][n] = MFMA_B16(af2, bf0[n], acc[2][n]);
            acc[3][n] = MFMA_B16(af3, bf0[n], acc[3][n]);
        }
        __builtin_amdgcn_s_setprio(0);
        __builtin_amdgcn_sched_barrier(0);

        // ---- Ph2: ds_read h1 {B n0..3, A m0,m1}; MFMA h1 m01
        short8 bf1[4], ag0, ag1;
        #pragma unroll
        for (int n = 0; n < 4; ++n)
            bf1[n] = *(const short8*)((const char*)Bb + ofsB[n][1]);
        ag0 = *(const short8*)((const char*)Ab + ofsA[0][1]);
        ag1 = *(const short8*)((const char*)Ab + ofsA[1][1]);
        __builtin_amdgcn_sched_barrier(0);
        __builtin_amdgcn_s_barrier();
        __builtin_amdgcn_s_setprio(1);
        #pragma unroll
        for (int n = 0; n < 4; ++n) {
            acc[0][n] = MFMA_B16(ag0, bf1[n], acc[0][n]);
            acc[1][n] = MFMA_B16(ag1, bf1[n], acc[1][n]);
        }
        __builtin_amdgcn_s_setprio(0);
        __builtin_amdgcn_sched_barrier(0);

        // ---- Ph3: ds_read h1 {A m2,m3}; MFMA h1 m23; A-next cvt+write
        short8 ag2 = *(const short8*)((const char*)Ab + ofsA[2][1]);
        short8 ag3 = *(const short8*)((const char*)Ab + ofsA[3][1]);
        __builtin_amdgcn_sched_barrier(0);
        __builtin_amdgcn_s_barrier();
        __builtin_amdgcn_s_setprio(1);
        #pragma unroll
        for (int n = 0; n < 4; ++n) {
            acc[2][n] = MFMA_B16(ag2, bf1[n], acc[2][n]);
            acc[3][n] = MFMA_B16(ag3, bf1[n], acc[3][n]);
        }
        __builtin_amdgcn_s_setprio(0);
        if (have) {
            u32x4 w = (u32x4){pkbf(an0.x, an0.y), pkbf(an0.z, an0.w),
                              pkbf(an1.x, an1.y), pkbf(an1.z, an1.w)};
            *(u32x4*)((char*)As[buf ^ 1] + dstA) = w;   // drained by next sync
        }
        buf ^= 1;
    }

    // epilogue: tanh(acc + uh) * Vk -> per-row partials
    // C/D layout: col = lane&15, row = quad*4 + reg   [m89-verified]
    float uhv[4], vkv[4];
    #pragma unroll
    for (int tn = 0; tn < 4; ++tn) {
        const int nl = wn * 64 + tn * 16 + lc;
        uhv[tn] = uh[bidx * 512 + nl];
        vkv[tn] = Vk[nl];
    }
    float rp[16];
    #pragma unroll
    for (int i = 0; i < 16; ++i) rp[i] = 0.f;
    #pragma unroll
    for (int tn = 0; tn < 4; ++tn) {
        #pragma unroll
        for (int tm = 0; tm < 4; ++tm)
            #pragma unroll
            for (int i = 0; i < 4; ++i) {
                const float x = acc[tm][tn][i] + uhv[tn];
                const float e = __expf(2.0f * x);          // tanh = 1 - 2/(e^{2x}+1)
                rp[tm * 4 + i] += (1.0f - 2.0f / (e + 1.0f)) * vkv[tn];
            }
    }
    #pragma unroll
    for (int i = 0; i < 16; ++i) {
        float v = rp[i];
        v += __shfl_xor(v, 1, 64);
        v += __shfl_xor(v, 2, 64);
        v += __shfl_xor(v, 4, 64);
        v += __shfl_xor(v, 8, 64);
        rp[i] = v;
    }
    __syncthreads();                        // all As reads done -> overlay ok
    float* lp = (float*)(&As[0][0]);        // lpart[8][128] overlays As
    if (lc == 0) {
        #pragma unroll
        for (int tm = 0; tm < 4; ++tm)
            #pragma unroll
            for (int i = 0; i < 4; ++i)
                lp[wn * 128 + wm * 64 + tm * 16 + quad * 4 + i] = rp[tm * 4 + i];
    }
    __syncthreads();
    if (tid < 128) {
        float s = 0.f;
        #pragma unroll
        for (int j = 0; j < 8; ++j) s += lp[j * 128 + tid];
        lg[m0 + tid] = s;
    }
}

// ---------------------------------------------------------------- softmax
__global__ __launch_bounds__(256) void softmax_k(
    const float* __restrict__ lg, float* __restrict__ aw_out)
{
    const int b = blockIdx.x, tid = threadIdx.x;
    const float* p = lg + b * 2048;
    float v[8];
    #pragma unroll
    for (int i = 0; i < 8; ++i) v[i] = p[tid + i * 256];
    float mx = -1e30f;
    #pragma unroll
    for (int i = 0; i < 8; ++i) mx = fmaxf(mx, v[i]);
    #pragma unroll
    for (int off = 32; off >= 1; off >>= 1) mx = fmaxf(mx, __shfl_xor(mx, off, 64));
    __shared__ float redm[4], reds[4];
    const int wv = tid >> 6, ln = tid & 63;
    if (ln == 0) redm[wv] = mx;
    __syncthreads();
    mx = fmaxf(fmaxf(redm[0], redm[1]), fmaxf(redm[2], redm[3]));
    float s = 0.f;
    #pragma unroll
    for (int i = 0; i < 8; ++i) { v[i] = __expf(v[i] - mx); s += v[i]; }
    #pragma unroll
    for (int off = 32; off >= 1; off >>= 1) s += __shfl_xor(s, off, 64);
    if (ln == 0) reds[wv] = s;
    __syncthreads();
    s = reds[0] + reds[1] + reds[2] + reds[3];
    const float inv = 1.0f / s;
    #pragma unroll
    for (int i = 0; i < 8; ++i)
        aw_out[b * 2048 + tid + i * 256] = v[i] * inv;
}

// ------------------------------------------------------- context, stage 1
__global__ __launch_bounds__(256) void context_part(
    const float* __restrict__ feats, const float* __restrict__ aw,
    float* __restrict__ part)
{
    const int b     = blockIdx.x >> 4;
    const int chunk = blockIdx.x & 15;
    const int half  = threadIdx.x >> 7;
    const int t0    = chunk * 128 + half * 64;
    const int d4    = (threadIdx.x & 127) * 4;
    const float* wp = aw + b * 2048 + t0;
    const float* fp = feats + (size_t)(b * 2048 + t0) * 512 + d4;
    f32x4 a = (f32x4){0.f, 0.f, 0.f, 0.f};
    #pragma unroll 4
    for (int tt = 0; tt < 64; ++tt) {
        const float w = wp[tt];
        const f32x4 f = *(const f32x4*)(fp + (size_t)tt * 512);
        a.x += w * f.x; a.y += w * f.y; a.z += w * f.z; a.w += w * f.w;
    }
    *(f32x4*)(part + (size_t)(b * 32 + chunk * 2 + half) * 512 + d4) = a;
}

// ------------------------------------------------------- context, stage 2
__global__ __launch_bounds__(512) void context_reduce(
    const float* __restrict__ part, float* __restrict__ ctx)
{
    const int b = blockIdx.x;
    const int d = threadIdx.x;
    const float* p = part + (size_t)b * 32 * 512 + d;
    float s = 0.f;
    #pragma unroll
    for (int j = 0; j < 32; ++j) s += p[j * 512];
    ctx[b * 512 + d] = s;
}

// ---------------------------------------------------------------- launch
extern "C" void kernel_launch(void* const* d_in, const int* in_sizes, int n_in,
                              void* d_out, int out_size, void* d_ws, size_t ws_size,
                              hipStream_t stream)
{
    const float* feats  = (const float*)d_in[0];
    const float* hidden = (const float*)d_in[1];
    const float* Wk     = (const float*)d_in[2];
    const float* Wb     = (const float*)d_in[3];
    const float* Uk     = (const float*)d_in[4];
    const float* Ub     = (const float*)d_in[5];
    const float* Vk     = (const float*)d_in[6];
    // d_in[7] = Vb: constant logit shift, cancels in softmax.

    float* out       = (float*)d_out;
    float* ctx_out_p = out;               // [32*512]  fp32
    float* aw_out_p  = out + 16384;       // [32*2048] fp32

    char* ws = (char*)d_ws;
    float*    uh   = (float*)ws;                      // 64 KB
    ushort_t* WkT  = (ushort_t*)(ws + 65536);         // 512 KB
    float*    lg   = (float*)(ws + 589824);           // 256 KB
    float*    part = (float*)(ws + 851968);           // 2 MB  (32*32*512 f32)

    prep_all      <<<512, 256, 0, stream>>>(hidden, Uk, Ub, Wb, Wk, uh, WkT);
    attn_gemm     <<<512, 1024, 0, stream>>>(feats, WkT, uh, Vk, lg);
    softmax_k     <<<32,  256, 0, stream>>>(lg, aw_out_p);
    context_part  <<<512, 256, 0, stream>>>(feats, aw_out_p, part);
    context_reduce<<<32,  512, 0, stream>>>(part, ctx_out_p);
}

// Round 9
// 258.984 us; speedup vs baseline: 1.1253x; 1.1253x over previous
//
#include <hip/hip_runtime.h>
#include <stdint.h>

// Bahdanau additive attention, MI355X / gfx950.
// Inputs fp32, outputs fp32 (ctx[32*512] ++ aw[32*2048]).
// B=32, T=2048, D=512, U=512.  M = B*T = 65536.
//
// R17: REVERT to the session's best-verified kernel (Round-2 state, 255.9us):
//      R2 attn_gemm (77us) + atomic-free tail. Per R7 pre-commitment after
//      R16's failure. R16 diagnostics that close the gemm investigation:
//      conflicts 2.6M->0 (swizzle proven correct, ~5% effect only) but
//      WRITE_SIZE 256KB->70MB = register spills: the 4-phase live set
//      (~140 VGPR) exceeds the 128-VGPR hard cap of 1024-thread blocks.
//      Deep pipelining here requires a 512-thread / 128x64-per-wave ground-up
//      redesign (HK-class co-design; corpus m232: unreproduced at this tile).
//      Six gemm attempts (R11/R12/R13/R15/R16) all regressed vs R2's 77us.
// R10: context atomics removed (-4.4us). R8: B LDS XOR-swizzle.

typedef unsigned short ushort_t;
typedef __attribute__((ext_vector_type(8))) short short8;
typedef __attribute__((ext_vector_type(4))) float f32x4;
typedef __attribute__((ext_vector_type(2))) float float2v;
typedef __attribute__((ext_vector_type(2))) __bf16 bf162v;

#define GLOBAL_AS __attribute__((address_space(1)))
#define LDS_AS    __attribute__((address_space(3)))

__device__ __forceinline__ ushort_t f2bf(float f) {
    uint32_t u = __builtin_bit_cast(uint32_t, f);
    u = (u + 0x7fffu + ((u >> 16) & 1u)) >> 16;   // RNE
    return (ushort_t)u;
}
__device__ __forceinline__ uint32_t pkbf(float a, float b) {
    bf162v r = __builtin_convertvector((float2v){a, b}, bf162v);
    return __builtin_bit_cast(uint32_t, r);
}

// --------------------------- fused prep: uh GEMV + WkT transpose
// grid 512 = 256 uh | 256 WkT
__global__ __launch_bounds__(256) void prep_all(
    const float* __restrict__ hidden, const float* __restrict__ Uk,
    const float* __restrict__ Ub, const float* __restrict__ Wb,
    const float* __restrict__ Wk,
    float* __restrict__ uh, ushort_t* __restrict__ WkT)
{
    const int pb = blockIdx.x;
    if (pb < 256) {
        // uh[b][u] = hidden[b]·Uk[:,u] + Ub[u] + Wb[u]
        const int b  = pb >> 3;
        const int u  = (pb & 7) * 64 + (threadIdx.x & 63);
        const int k0 = (threadIdx.x >> 6) * 128;
        const float* hr = hidden + b * 512;
        float acc = 0.f;
        #pragma unroll 8
        for (int k = k0; k < k0 + 128; ++k)
            acc += hr[k] * Uk[k * 512 + u];
        __shared__ float red[256];
        red[threadIdx.x] = acc;
        __syncthreads();
        if (threadIdx.x < 64) {
            const int ul = threadIdx.x;
            uh[b * 512 + u] = red[ul] + red[ul + 64] + red[ul + 128] + red[ul + 192]
                            + Ub[u] + Wb[u];
        }
    } else {
        // WkT[u][d] = bf16(Wk[d][u]) via 32x32 LDS tile
        __shared__ float t[32][33];
        const int blk = pb - 256;
        const int ti = blk >> 4;
        const int tj = blk & 15;
        const int tx = threadIdx.x & 31;
        const int ty = threadIdx.x >> 5;
        #pragma unroll
        for (int q = 0; q < 4; ++q) {
            const int r = ty * 4 + q;
            t[r][tx] = Wk[(ti * 32 + r) * 512 + tj * 32 + tx];
        }
        __syncthreads();
        #pragma unroll
        for (int q = 0; q < 4; ++q) {
            const int r = ty * 4 + q;
            WkT[(tj * 32 + r) * 512 + ti * 32 + tx] = f2bf(t[tx][r]);
        }
    }
}

// ------------------------------------------------ fused GEMM+tanh+Vk-dot
// grid 512 M-tiles of 128 rows; 1024 threads = 16 waves (2M x 8N, 64x64 each).
// All N=512 held in acc. A fp32->bf16 in-kernel; B double-buffered + swizzled.
#define APAD 40   // A row stride in shorts (2-way banks = free)
__global__ __launch_bounds__(1024, 4) void attn_gemm(
    const float* __restrict__ feats, const ushort_t* __restrict__ WkT,
    const float* __restrict__ uh, const float* __restrict__ Vk,
    float* __restrict__ lg)
{
    __shared__ __align__(16) short As[2][128 * APAD];
    __shared__ __align__(16) short Bs[2][512 * 32];
    __shared__ float uh_s[512];
    __shared__ float vk_s[512];
    __shared__ float lpart[8][128];

    const int tid  = threadIdx.x;
    const int lane = tid & 63;
    const int quad = lane >> 4;
    const int lc   = lane & 15;
    const int wave = tid >> 6;       // 0..15
    const int wm   = wave >> 3;      // 0..1  (64-row strip)
    const int wn   = wave & 7;       // 0..7  (64-col strip)
    const int m0   = blockIdx.x * 128;
    const int bidx = m0 >> 11;       // batch index (uniform per block)

    if (tid < 512) {
        uh_s[tid] = uh[bidx * 512 + tid];
        vk_s[tid] = Vk[tid];
    }

    const int rowA = tid >> 3;          // 0..127
    const int kAo  = (tid & 7) * 4;     // fp32 k-offset 0..28
    // B staging swizzle: lds slot s of row r holds global k-slot s ^ ((r>>1)&3)
    const int rB0  = tid >> 2;          // rnd 0 row (0..255)
    const int sB   = tid & 3;           // lds k-slot

    f32x4 acc[4][4];
    #pragma unroll
    for (int tm = 0; tm < 4; ++tm)
        #pragma unroll
        for (int tn = 0; tn < 4; ++tn)
            acc[tm][tn] = (f32x4){0.f, 0.f, 0.f, 0.f};

    // ---- prologue: stage chunk 0 into buf 0
    {
        #pragma unroll
        for (int rnd = 0; rnd < 2; ++rnd) {
            const int li = rnd * 1024 + tid;
            const int rB = rnd * 256 + rB0;
            const int kq = (sB ^ ((rB >> 1) & 3)) * 8;
            const ushort_t* gb = WkT + (size_t)rB * 512 + kq;
            __builtin_amdgcn_global_load_lds(
                (const GLOBAL_AS void*)gb, (LDS_AS void*)(Bs[0] + li * 8), 16, 0, 0);
        }
        const f32x4 av = *(const f32x4*)(feats + (size_t)(m0 + rowA) * 512 + kAo);
        uint2 w;
        w.x = pkbf(av.x, av.y);
        w.y = pkbf(av.z, av.w);
        *(uint2*)(As[0] + rowA * APAD + kAo) = w;
    }

    const int swzR = (lc >> 1) & 3;     // fragment-read swizzle (row = ...+lc)

    int buf = 0;
    for (int ks = 0; ks < 16; ++ks) {   // K = 512, BK = 32
        __syncthreads();                // staging of `buf` complete

        f32x4 a_next;
        const bool have = (ks + 1) < 16;
        if (have) {
            const int k0n = (ks + 1) * 32;
            #pragma unroll
            for (int rnd = 0; rnd < 2; ++rnd) {
                const int li = rnd * 1024 + tid;
                const int rB = rnd * 256 + rB0;
                const int kq = (sB ^ ((rB >> 1) & 3)) * 8;
                const ushort_t* gb = WkT + (size_t)rB * 512 + k0n + kq;
                __builtin_amdgcn_global_load_lds(
                    (const GLOBAL_AS void*)gb, (LDS_AS void*)(Bs[buf ^ 1] + li * 8),
                    16, 0, 0);
            }
            a_next = *(const f32x4*)(feats + (size_t)(m0 + rowA) * 512 + k0n + kAo);
        }

        // ---- compute on `buf` (hides the loads above)
        short8 af[4], bfr[4];
        #pragma unroll
        for (int t4 = 0; t4 < 4; ++t4) {
            af[t4]  = *(const short8*)(As[buf] + (wm * 64 + t4 * 16 + lc) * APAD + quad * 8);
            bfr[t4] = *(const short8*)(Bs[buf] + (wn * 64 + t4 * 16 + lc) * 32
                                       + ((quad ^ swzR) * 8));
        }
        #pragma unroll
        for (int tm = 0; tm < 4; ++tm)
            #pragma unroll
            for (int tn = 0; tn < 4; ++tn)
                acc[tm][tn] = __builtin_amdgcn_mfma_f32_16x16x32_bf16(
                    af[tm], bfr[tn], acc[tm][tn], 0, 0, 0);

        if (have) {
            uint2 w;
            w.x = pkbf(a_next.x, a_next.y);
            w.y = pkbf(a_next.z, a_next.w);
            *(uint2*)(As[buf ^ 1] + rowA * APAD + kAo) = w;
        }
        buf ^= 1;
    }

    // epilogue: tanh(acc + uh) * Vk -> per-row partials
    // C/D layout: col = lane&15, row = quad*4 + reg   [m89-verified]
    float rp[16];
    #pragma unroll
    for (int i = 0; i < 16; ++i) rp[i] = 0.f;
    #pragma unroll
    for (int tn = 0; tn < 4; ++tn) {
        const int nl  = wn * 64 + tn * 16 + lc;
        const float uhv = uh_s[nl];
        const float vkv = vk_s[nl];
        #pragma unroll
        for (int tm = 0; tm < 4; ++tm)
            #pragma unroll
            for (int i = 0; i < 4; ++i) {
                const float x = acc[tm][tn][i] + uhv;
                const float e = __expf(2.0f * x);          // tanh = 1 - 2/(e^{2x}+1)
                rp[tm * 4 + i] += (1.0f - 2.0f / (e + 1.0f)) * vkv;
            }
    }
    #pragma unroll
    for (int i = 0; i < 16; ++i) {
        float v = rp[i];
        v += __shfl_xor(v, 1, 64);
        v += __shfl_xor(v, 2, 64);
        v += __shfl_xor(v, 4, 64);
        v += __shfl_xor(v, 8, 64);
        rp[i] = v;
    }
    if (lc == 0) {
        #pragma unroll
        for (int tm = 0; tm < 4; ++tm)
            #pragma unroll
            for (int i = 0; i < 4; ++i)
                lpart[wn][wm * 64 + tm * 16 + quad * 4 + i] = rp[tm * 4 + i];
    }
    __syncthreads();
    if (tid < 128) {
        float s = 0.f;
        #pragma unroll
        for (int j = 0; j < 8; ++j) s += lpart[j][tid];
        lg[m0 + tid] = s;
    }
}

// ---------------------------------------------------------------- softmax
__global__ __launch_bounds__(256) void softmax_k(
    const float* __restrict__ lg, float* __restrict__ aw_out)
{
    const int b = blockIdx.x, tid = threadIdx.x;
    const float* p = lg + b * 2048;
    float v[8];
    #pragma unroll
    for (int i = 0; i < 8; ++i) v[i] = p[tid + i * 256];
    float mx = -1e30f;
    #pragma unroll
    for (int i = 0; i < 8; ++i) mx = fmaxf(mx, v[i]);
    #pragma unroll
    for (int off = 32; off >= 1; off >>= 1) mx = fmaxf(mx, __shfl_xor(mx, off, 64));
    __shared__ float redm[4], reds[4];
    const int wv = tid >> 6, ln = tid & 63;
    if (ln == 0) redm[wv] = mx;
    __syncthreads();
    mx = fmaxf(fmaxf(redm[0], redm[1]), fmaxf(redm[2], redm[3]));
    float s = 0.f;
    #pragma unroll
    for (int i = 0; i < 8; ++i) { v[i] = __expf(v[i] - mx); s += v[i]; }
    #pragma unroll
    for (int off = 32; off >= 1; off >>= 1) s += __shfl_xor(s, off, 64);
    if (ln == 0) reds[wv] = s;
    __syncthreads();
    s = reds[0] + reds[1] + reds[2] + reds[3];
    const float inv = 1.0f / s;
    #pragma unroll
    for (int i = 0; i < 8; ++i)
        aw_out[b * 2048 + tid + i * 256] = v[i] * inv;
}

// ------------------------------------------------------- context, stage 1
// grid 512 = 32 b x 16 t-chunks(128); two 64-t halves per block write
// DISJOINT partial slots (no atomics). part[b][chunk*2+half][d].
__global__ __launch_bounds__(256) void context_part(
    const float* __restrict__ feats, const float* __restrict__ aw,
    float* __restrict__ part)
{
    const int b     = blockIdx.x >> 4;
    const int chunk = blockIdx.x & 15;
    const int half  = threadIdx.x >> 7;
    const int t0    = chunk * 128 + half * 64;
    const int d4    = (threadIdx.x & 127) * 4;
    const float* wp = aw + b * 2048 + t0;
    const float* fp = feats + (size_t)(b * 2048 + t0) * 512 + d4;
    f32x4 a = (f32x4){0.f, 0.f, 0.f, 0.f};
    #pragma unroll 4
    for (int tt = 0; tt < 64; ++tt) {
        const float w = wp[tt];
        const f32x4 f = *(const f32x4*)(fp + (size_t)tt * 512);
        a.x += w * f.x; a.y += w * f.y; a.z += w * f.z; a.w += w * f.w;
    }
    *(f32x4*)(part + (size_t)(b * 32 + chunk * 2 + half) * 512 + d4) = a;
}

// ------------------------------------------------------- context, stage 2
// grid 32 (b) x 512 threads (d): ctx[b][d] = sum_j part[b][j][d], j<32.
__global__ __launch_bounds__(512) void context_reduce(
    const float* __restrict__ part, float* __restrict__ ctx)
{
    const int b = blockIdx.x;
    const int d = threadIdx.x;
    const float* p = part + (size_t)b * 32 * 512 + d;
    float s = 0.f;
    #pragma unroll
    for (int j = 0; j < 32; ++j) s += p[j * 512];
    ctx[b * 512 + d] = s;
}

// ---------------------------------------------------------------- launch
extern "C" void kernel_launch(void* const* d_in, const int* in_sizes, int n_in,
                              void* d_out, int out_size, void* d_ws, size_t ws_size,
                              hipStream_t stream)
{
    const float* feats  = (const float*)d_in[0];
    const float* hidden = (const float*)d_in[1];
    const float* Wk     = (const float*)d_in[2];
    const float* Wb     = (const float*)d_in[3];
    const float* Uk     = (const float*)d_in[4];
    const float* Ub     = (const float*)d_in[5];
    const float* Vk     = (const float*)d_in[6];
    // d_in[7] = Vb: constant logit shift, cancels in softmax.

    float* out       = (float*)d_out;
    float* ctx_out_p = out;               // [32*512]  fp32
    float* aw_out_p  = out + 16384;       // [32*2048] fp32

    char* ws = (char*)d_ws;
    float*    uh   = (float*)ws;                      // 64 KB
    ushort_t* WkT  = (ushort_t*)(ws + 65536);         // 512 KB
    float*    lg   = (float*)(ws + 589824);           // 256 KB
    float*    part = (float*)(ws + 851968);           // 2 MB  (32*32*512 f32)

    prep_all      <<<512, 256, 0, stream>>>(hidden, Uk, Ub, Wb, Wk, uh, WkT);
    attn_gemm     <<<512, 1024, 0, stream>>>(feats, WkT, uh, Vk, lg);
    softmax_k     <<<32,  256, 0, stream>>>(lg, aw_out_p);
    context_part  <<<512, 256, 0, stream>>>(feats, aw_out_p, part);
    context_reduce<<<32,  512, 0, stream>>>(part, ctx_out_p);
}